// Round 1
// baseline (569.878 us; speedup 1.0000x reference)
//
#include <hip/hip_runtime.h>
#include <math.h>

// ---------------------------------------------------------------------------
// GCN 3-layer forward:  h = relu(Ahat @ (x @ W) + b)  x3
// Ahat = D^-1/2 (A + I) D^-1/2, built as CSR-by-dst once per launch.
// ---------------------------------------------------------------------------

__global__ void zero2_kernel(int* __restrict__ a, int* __restrict__ b, int n) {
    int i = blockIdx.x * blockDim.x + threadIdx.x;
    if (i < n) { a[i] = 0; b[i] = 0; }
}

__global__ void deg_kernel(const int* __restrict__ dst, int* __restrict__ deg, int E) {
    int i = blockIdx.x * blockDim.x + threadIdx.x;
    if (i < E) atomicAdd(&deg[dst[i]], 1);
}

__global__ void dinv_kernel(const int* __restrict__ deg, float* __restrict__ dinv, int n) {
    int i = blockIdx.x * blockDim.x + threadIdx.x;
    // self-loop adds 1 to every node's degree -> always > 0
    if (i < n) dinv[i] = 1.0f / sqrtf((float)(deg[i] + 1));
}

// Single-block inclusive scan over (deg[i]+1) -> row_ptr[0..n], row_ptr[0]=0.
__global__ __launch_bounds__(1024) void scan_kernel(const int* __restrict__ deg,
                                                    int* __restrict__ row_ptr, int n) {
    __shared__ int sdata[1024];
    __shared__ int s_running;
    int tid = threadIdx.x;
    if (tid == 0) { s_running = 0; row_ptr[0] = 0; }
    __syncthreads();
    for (int base = 0; base < n; base += 1024) {
        int i = base + tid;
        int v = (i < n) ? (deg[i] + 1) : 0;
        sdata[tid] = v;
        __syncthreads();
        for (int off = 1; off < 1024; off <<= 1) {
            int t = (tid >= off) ? sdata[tid - off] : 0;
            __syncthreads();
            sdata[tid] += t;
            __syncthreads();
        }
        if (i < n) row_ptr[i + 1] = s_running + sdata[tid];
        __syncthreads();
        if (tid == 0) s_running += sdata[1023];
        __syncthreads();
    }
}

// Scatter edges (and self-loops) into CSR slots. Order within a row is
// atomic-arrival order (fp-sum reorder only; well within threshold).
__global__ void fill_kernel(const int* __restrict__ ei, const float* __restrict__ dinv,
                            const int* __restrict__ row_ptr, int* __restrict__ counter,
                            int* __restrict__ csr_col, float* __restrict__ csr_w,
                            int E, int n) {
    int idx = blockIdx.x * blockDim.x + threadIdx.x;
    int total = E + n;
    if (idx >= total) return;
    int s, d;
    if (idx < E) { s = ei[idx]; d = ei[E + idx]; }
    else         { s = d = idx - E; }
    int pos = row_ptr[d] + atomicAdd(&counter[d], 1);
    csr_col[pos] = s;
    csr_w[pos]   = dinv[s] * dinv[d];
}

// ---------------------------------------------------------------------------
// Tiled fp32 GEMM: C[M,N] = A[M,K] @ B[K,N].  Requires K%32==0, N%64==0.
// block 256 threads -> 64x64 tile, 4x4 micro-tile per thread.
// A staged transposed As[k][m] (conflict-free stores, broadcast reads).
// ---------------------------------------------------------------------------
#define GT 64
#define KC 32
__global__ __launch_bounds__(256) void gemm_kernel(const float* __restrict__ A,
                                                   const float* __restrict__ B,
                                                   float* __restrict__ C,
                                                   int M, int K, int N) {
    __shared__ float As[KC][GT + 1];   // [k][m], stride 65 -> conflict-free stores
    __shared__ float Bs[KC][GT + 4];   // [k][n], stride 68 -> 16B-aligned rows
    int tid = threadIdx.x;
    int tx = tid & 15;         // 16 col-groups of 4
    int ty = tid >> 4;         // 16 row-groups of 4
    int row0 = blockIdx.x * GT;
    int col0 = blockIdx.y * GT;

    float acc[4][4] = {};

    for (int kc = 0; kc < K; kc += KC) {
        // stage A: 64 rows x 32 k.  lanes contiguous in k -> coalesced.
        int ca = tid & 31;
        int ra0 = tid >> 5;
        #pragma unroll
        for (int i = 0; i < 8; ++i) {
            int r = ra0 + i * 8;
            int gr = row0 + r;
            float v = (gr < M) ? A[(size_t)gr * K + kc + ca] : 0.0f;
            As[ca][r] = v;
        }
        // stage B: 32 k x 64 cols.  lanes contiguous in n -> coalesced.
        int cb = tid & 63;
        int rb0 = tid >> 6;
        #pragma unroll
        for (int i = 0; i < 8; ++i) {
            int r = rb0 + i * 4;
            Bs[r][cb] = B[(size_t)(kc + r) * N + col0 + cb];
        }
        __syncthreads();

        #pragma unroll
        for (int kk = 0; kk < KC; ++kk) {
            float a[4], b[4];
            #pragma unroll
            for (int j = 0; j < 4; ++j) a[j] = As[kk][ty * 4 + j];
            #pragma unroll
            for (int j = 0; j < 4; ++j) b[j] = Bs[kk][tx * 4 + j];
            #pragma unroll
            for (int x = 0; x < 4; ++x)
                #pragma unroll
                for (int y = 0; y < 4; ++y)
                    acc[x][y] += a[x] * b[y];
        }
        __syncthreads();
    }

    #pragma unroll
    for (int x = 0; x < 4; ++x) {
        int gr = row0 + ty * 4 + x;
        if (gr < M) {
            float4 v = make_float4(acc[x][0], acc[x][1], acc[x][2], acc[x][3]);
            *(float4*)(&C[(size_t)gr * N + col0 + tx * 4]) = v;
        }
    }
}

// ---------------------------------------------------------------------------
// SpMM + bias + relu: out[n,:] = relu( sum_e w[e]*H[col[e],:] + bias )
// one wave per node; F=128 -> float2/lane, F=64 -> float/lane.
// ---------------------------------------------------------------------------
template <int F>
__global__ __launch_bounds__(256) void spmm_kernel(const float* __restrict__ H,
                                                   const int* __restrict__ row_ptr,
                                                   const int* __restrict__ csr_col,
                                                   const float* __restrict__ csr_w,
                                                   const float* __restrict__ bias,
                                                   float* __restrict__ out,
                                                   int n_nodes) {
    int wave = threadIdx.x >> 6;
    int lane = threadIdx.x & 63;
    int node = blockIdx.x * 4 + wave;
    if (node >= n_nodes) return;

    int e0 = row_ptr[node];
    int e1 = row_ptr[node + 1];

    if constexpr (F == 128) {
        float2 acc = make_float2(0.0f, 0.0f);
        for (int e = e0; e < e1; ++e) {
            int   c = csr_col[e];
            float w = csr_w[e];
            float2 v = *(const float2*)(H + (size_t)c * F + 2 * lane);
            acc.x += w * v.x;
            acc.y += w * v.y;
        }
        float bx = bias[2 * lane], by = bias[2 * lane + 1];
        float2 o;
        o.x = fmaxf(acc.x + bx, 0.0f);
        o.y = fmaxf(acc.y + by, 0.0f);
        *(float2*)(out + (size_t)node * F + 2 * lane) = o;
    } else {
        float acc = 0.0f;
        for (int e = e0; e < e1; ++e) {
            int   c = csr_col[e];
            float w = csr_w[e];
            acc += w * H[(size_t)c * F + lane];
        }
        float v = fmaxf(acc + bias[lane], 0.0f);
        out[(size_t)node * F + lane] = v;
    }
}

// ---------------------------------------------------------------------------

extern "C" void kernel_launch(void* const* d_in, const int* in_sizes, int n_in,
                              void* d_out, int out_size, void* d_ws, size_t ws_size,
                              hipStream_t stream) {
    const float* x  = (const float*)d_in[0];
    const int*   ei = (const int*)d_in[1];     // [2, E] int32 (JAX x64 disabled)
    const float* W1 = (const float*)d_in[2];
    const float* b1 = (const float*)d_in[3];
    const float* W2 = (const float*)d_in[4];
    const float* b2 = (const float*)d_in[5];
    const float* W3 = (const float*)d_in[6];
    const float* b3 = (const float*)d_in[7];

    const int IN_DIM = 256, HID = 128, OUT = 64;
    int n_nodes = in_sizes[0] / IN_DIM;    // 50000
    int n_edges = in_sizes[1] / 2;         // 800000
    int total_nnz = n_edges + n_nodes;     // edges + self-loops

    // workspace carve-up
    char* ws = (char*)d_ws;
    size_t off = 0;
    auto carve = [&](size_t bytes) { void* p = ws + off; off += (bytes + 255) & ~(size_t)255; return p; };
    float* Hbuf    = (float*)carve((size_t)n_nodes * HID * sizeof(float));
    float* Bbuf    = (float*)carve((size_t)n_nodes * HID * sizeof(float));
    int*   deg     = (int*)carve((size_t)n_nodes * sizeof(int));
    float* dinv    = (float*)carve((size_t)n_nodes * sizeof(float));
    int*   row_ptr = (int*)carve((size_t)(n_nodes + 1) * sizeof(int));
    int*   counter = (int*)carve((size_t)n_nodes * sizeof(int));
    int*   csr_col = (int*)carve((size_t)total_nnz * sizeof(int));
    float* csr_w   = (float*)carve((size_t)total_nnz * sizeof(float));
    if (off > ws_size) return;  // workspace too small; fail loudly via validation

    float* out = (float*)d_out;

    const int B = 256;
    // ---- graph preprocessing ----
    zero2_kernel<<<(n_nodes + B - 1) / B, B, 0, stream>>>(deg, counter, n_nodes);
    deg_kernel<<<(n_edges + B - 1) / B, B, 0, stream>>>(ei + n_edges, deg, n_edges);
    dinv_kernel<<<(n_nodes + B - 1) / B, B, 0, stream>>>(deg, dinv, n_nodes);
    scan_kernel<<<1, 1024, 0, stream>>>(deg, row_ptr, n_nodes);
    fill_kernel<<<(total_nnz + B - 1) / B, B, 0, stream>>>(ei, dinv, row_ptr, counter,
                                                           csr_col, csr_w, n_edges, n_nodes);

    int spmm_grid = (n_nodes + 3) / 4;

    // ---- layer 1: H = x @ W1 ; B1 = relu(Ahat H + b1) ----
    {
        dim3 g((n_nodes + GT - 1) / GT, HID / GT);
        gemm_kernel<<<g, 256, 0, stream>>>(x, W1, Hbuf, n_nodes, IN_DIM, HID);
        spmm_kernel<128><<<spmm_grid, 256, 0, stream>>>(Hbuf, row_ptr, csr_col, csr_w, b1, Bbuf, n_nodes);
    }
    // ---- layer 2 ----
    {
        dim3 g((n_nodes + GT - 1) / GT, HID / GT);
        gemm_kernel<<<g, 256, 0, stream>>>(Bbuf, W2, Hbuf, n_nodes, HID, HID);
        spmm_kernel<128><<<spmm_grid, 256, 0, stream>>>(Hbuf, row_ptr, csr_col, csr_w, b2, Bbuf, n_nodes);
    }
    // ---- layer 3 ----
    {
        dim3 g((n_nodes + GT - 1) / GT, OUT / GT);
        gemm_kernel<<<g, 256, 0, stream>>>(Bbuf, W3, Hbuf, n_nodes, HID, OUT);
        spmm_kernel<64><<<spmm_grid, 256, 0, stream>>>(Hbuf, row_ptr, csr_col, csr_w, b3, out, n_nodes);
    }
}

// Round 2
// 366.841 us; speedup vs baseline: 1.5535x; 1.5535x over previous
//
#include <hip/hip_runtime.h>
#include <math.h>

// ---------------------------------------------------------------------------
// GCN 3-layer forward:  h = relu(Ahat @ (x @ W) + b)  x3
// Ahat = D^-1/2 (A + I) D^-1/2, built as CSR-by-dst (rows padded to x4) once
// per launch. Padding slots have w=0, col=0 (arrays pre-zeroed) -> tail-free
// unroll-4 SpMM with 4 outstanding gathers per wave.
// ---------------------------------------------------------------------------

__global__ void zero2_kernel(int* __restrict__ a, int* __restrict__ b, int n) {
    int i = blockIdx.x * blockDim.x + threadIdx.x;
    if (i < n) { a[i] = 0; b[i] = 0; }
}

__global__ void deg_kernel(const int* __restrict__ dst, int* __restrict__ deg, int E) {
    int i = blockIdx.x * blockDim.x + threadIdx.x;
    if (i < E) atomicAdd(&deg[dst[i]], 1);
}

__global__ void dinv_kernel(const int* __restrict__ deg, float* __restrict__ dinv, int n) {
    int i = blockIdx.x * blockDim.x + threadIdx.x;
    if (i < n) dinv[i] = 1.0f / sqrtf((float)(deg[i] + 1));   // +1 self-loop
}

// --- 3-phase scan over padded row sizes: pad(i) = (deg[i]+1 + 3) & ~3 -------
__global__ __launch_bounds__(256) void scan1_kernel(const int* __restrict__ deg,
                                                    int* __restrict__ row_ptr,
                                                    int* __restrict__ partial, int n) {
    __shared__ int s[256];
    int tid = threadIdx.x;
    int i = blockIdx.x * 256 + tid;
    int v = (i < n) ? ((deg[i] + 4) & ~3) : 0;   // (deg+1) rounded up to mult of 4
    s[tid] = v;
    __syncthreads();
    #pragma unroll
    for (int off = 1; off < 256; off <<= 1) {
        int t = (tid >= off) ? s[tid - off] : 0;
        __syncthreads();
        s[tid] += t;
        __syncthreads();
    }
    if (i < n) row_ptr[i + 1] = s[tid];
    if (tid == 255) partial[blockIdx.x] = s[255];
}

__global__ __launch_bounds__(256) void scan2_kernel(int* __restrict__ partial, int nb) {
    __shared__ int s[256];
    int tid = threadIdx.x;
    int v = (tid < nb) ? partial[tid] : 0;
    s[tid] = v;
    __syncthreads();
    #pragma unroll
    for (int off = 1; off < 256; off <<= 1) {
        int t = (tid >= off) ? s[tid - off] : 0;
        __syncthreads();
        s[tid] += t;
        __syncthreads();
    }
    if (tid < nb) partial[tid] = s[tid] - v;     // exclusive
}

__global__ void scan3_kernel(const int* __restrict__ partial, int* __restrict__ row_ptr, int n) {
    int i = blockIdx.x * blockDim.x + threadIdx.x;
    if (i == 0) row_ptr[0] = 0;
    if (i < n) row_ptr[i + 1] += partial[i >> 8];
}

__global__ void fill_kernel(const int* __restrict__ ei, const float* __restrict__ dinv,
                            const int* __restrict__ row_ptr, int* __restrict__ counter,
                            int* __restrict__ csr_col, float* __restrict__ csr_w,
                            int E, int n) {
    int idx = blockIdx.x * blockDim.x + threadIdx.x;
    int total = E + n;
    if (idx >= total) return;
    int s, d;
    if (idx < E) { s = ei[idx]; d = ei[E + idx]; }
    else         { s = d = idx - E; }
    int pos = row_ptr[d] + atomicAdd(&counter[d], 1);
    csr_col[pos] = s;
    csr_w[pos]   = dinv[s] * dinv[d];
}

// ---------------------------------------------------------------------------
// Tiled fp32 GEMM: C[M,N] = A[M,K] @ B[K,N].  K%32==0, N%8==0.
// 256 threads -> 64x128 tile, 4x8 micro-tile. As transposed [k][m] with
// 16B-aligned stride -> all inner-loop LDS reads are ds_read_b128.
// ---------------------------------------------------------------------------
#define TM 64
#define TN 128
#define TK 32
__global__ __launch_bounds__(256) void gemm_kernel(const float* __restrict__ A,
                                                   const float* __restrict__ B,
                                                   float* __restrict__ C,
                                                   int M, int K, int N) {
    __shared__ float As[TK][TM + 4];   // [k][m], row stride 272 B (16B-aligned)
    __shared__ float Bs[TK][TN + 4];   // [k][n], row stride 528 B (16B-aligned)
    int tid = threadIdx.x;
    int tx = tid & 15;          // 16 col-groups of 8
    int ty = tid >> 4;          // 16 row-groups of 4
    int row0 = blockIdx.x * TM;
    int col0 = blockIdx.y * TN;

    float acc[4][8] = {};

    for (int kc = 0; kc < K; kc += TK) {
        // stage A: 64 rows x 32 k  (512 float4, 2/thread), transpose into As[k][m]
        #pragma unroll
        for (int i = 0; i < 2; ++i) {
            int f = tid + i * 256;
            int r = f >> 3;               // 0..63
            int k4 = (f & 7) * 4;         // 0..28
            int gr = row0 + r;
            float4 v = make_float4(0.f, 0.f, 0.f, 0.f);
            if (gr < M) v = *(const float4*)(A + (size_t)gr * K + kc + k4);
            As[k4 + 0][r] = v.x;
            As[k4 + 1][r] = v.y;
            As[k4 + 2][r] = v.z;
            As[k4 + 3][r] = v.w;
        }
        // stage B: 32 k x 128 cols (1024 float4, 4/thread)
        #pragma unroll
        for (int i = 0; i < 4; ++i) {
            int f = tid + i * 256;
            int r = f >> 5;               // 0..31
            int c4 = (f & 31) * 4;        // 0..124
            float4 v = make_float4(0.f, 0.f, 0.f, 0.f);
            if (col0 + c4 < N) v = *(const float4*)(B + (size_t)(kc + r) * N + col0 + c4);
            *(float4*)(&Bs[r][c4]) = v;
        }
        __syncthreads();

        #pragma unroll
        for (int kk = 0; kk < TK; ++kk) {
            float a[4], b[8];
            *(float4*)(a)     = *(const float4*)(&As[kk][ty * 4]);
            *(float4*)(b)     = *(const float4*)(&Bs[kk][tx * 8]);
            *(float4*)(b + 4) = *(const float4*)(&Bs[kk][tx * 8 + 4]);
            #pragma unroll
            for (int x = 0; x < 4; ++x)
                #pragma unroll
                for (int y = 0; y < 8; ++y)
                    acc[x][y] = fmaf(a[x], b[y], acc[x][y]);
        }
        __syncthreads();
    }

    #pragma unroll
    for (int x = 0; x < 4; ++x) {
        int gr = row0 + ty * 4 + x;
        int gc = col0 + tx * 8;
        if (gr < M && gc < N) {
            *(float4*)(&C[(size_t)gr * N + gc])     = *(float4*)(&acc[x][0]);
            *(float4*)(&C[(size_t)gr * N + gc + 4]) = *(float4*)(&acc[x][4]);
        }
    }
}

// ---------------------------------------------------------------------------
// SpMM + bias + relu, rows padded to x4: out[n,:] = relu(sum w*H[col,:] + b)
// one wave per node; 4 edges in flight per iteration (MLP x4).
// ---------------------------------------------------------------------------
template <int F>
__global__ __launch_bounds__(256) void spmm_kernel(const float* __restrict__ H,
                                                   const int* __restrict__ row_ptr,
                                                   const int* __restrict__ csr_col,
                                                   const float* __restrict__ csr_w,
                                                   const float* __restrict__ bias,
                                                   float* __restrict__ out,
                                                   int n_nodes) {
    int wave = threadIdx.x >> 6;
    int lane = threadIdx.x & 63;
    int node = (blockIdx.x << 2) + wave;
    if (node >= n_nodes) return;

    int e0 = row_ptr[node];
    int e1 = row_ptr[node + 1];

    if constexpr (F == 128) {
        const float* Hl = H + (lane << 1);
        float2 a0 = {0.f, 0.f}, a1 = {0.f, 0.f}, a2 = {0.f, 0.f}, a3 = {0.f, 0.f};
        for (int e = e0; e < e1; e += 4) {
            int4   c = *(const int4*)(csr_col + e);
            float4 w = *(const float4*)(csr_w + e);
            float2 v0 = *(const float2*)(Hl + (size_t)c.x * F);
            float2 v1 = *(const float2*)(Hl + (size_t)c.y * F);
            float2 v2 = *(const float2*)(Hl + (size_t)c.z * F);
            float2 v3 = *(const float2*)(Hl + (size_t)c.w * F);
            a0.x = fmaf(w.x, v0.x, a0.x); a0.y = fmaf(w.x, v0.y, a0.y);
            a1.x = fmaf(w.y, v1.x, a1.x); a1.y = fmaf(w.y, v1.y, a1.y);
            a2.x = fmaf(w.z, v2.x, a2.x); a2.y = fmaf(w.z, v2.y, a2.y);
            a3.x = fmaf(w.w, v3.x, a3.x); a3.y = fmaf(w.w, v3.y, a3.y);
        }
        float sx = (a0.x + a1.x) + (a2.x + a3.x) + bias[lane << 1];
        float sy = (a0.y + a1.y) + (a2.y + a3.y) + bias[(lane << 1) + 1];
        float2 o;
        o.x = fmaxf(sx, 0.0f);
        o.y = fmaxf(sy, 0.0f);
        *(float2*)(out + (size_t)node * F + (lane << 1)) = o;
    } else {  // F == 64
        const float* Hl = H + lane;
        float s0 = 0.f, s1 = 0.f, s2 = 0.f, s3 = 0.f;
        for (int e = e0; e < e1; e += 4) {
            int4   c = *(const int4*)(csr_col + e);
            float4 w = *(const float4*)(csr_w + e);
            float v0 = Hl[(size_t)c.x * F];
            float v1 = Hl[(size_t)c.y * F];
            float v2 = Hl[(size_t)c.z * F];
            float v3 = Hl[(size_t)c.w * F];
            s0 = fmaf(w.x, v0, s0);
            s1 = fmaf(w.y, v1, s1);
            s2 = fmaf(w.z, v2, s2);
            s3 = fmaf(w.w, v3, s3);
        }
        float v = fmaxf((s0 + s1) + (s2 + s3) + bias[lane], 0.0f);
        out[(size_t)node * F + lane] = v;
    }
}

// ---------------------------------------------------------------------------

extern "C" void kernel_launch(void* const* d_in, const int* in_sizes, int n_in,
                              void* d_out, int out_size, void* d_ws, size_t ws_size,
                              hipStream_t stream) {
    const float* x  = (const float*)d_in[0];
    const int*   ei = (const int*)d_in[1];     // [2, E] int32
    const float* W1 = (const float*)d_in[2];
    const float* b1 = (const float*)d_in[3];
    const float* W2 = (const float*)d_in[4];
    const float* b2 = (const float*)d_in[5];
    const float* W3 = (const float*)d_in[6];
    const float* b3 = (const float*)d_in[7];

    const int IN_DIM = 256, HID = 128, OUT = 64;
    int n_nodes = in_sizes[0] / IN_DIM;    // 50000
    int n_edges = in_sizes[1] / 2;         // 800000
    int nnz_cap = n_edges + 4 * n_nodes;   // padded CSR upper bound

    // workspace carve-up
    char* ws = (char*)d_ws;
    size_t off = 0;
    auto carve = [&](size_t bytes) { void* p = ws + off; off += (bytes + 255) & ~(size_t)255; return p; };
    float* Hbuf    = (float*)carve((size_t)n_nodes * HID * sizeof(float));
    float* Bbuf    = (float*)carve((size_t)n_nodes * HID * sizeof(float));
    int*   deg     = (int*)carve((size_t)n_nodes * sizeof(int));
    float* dinv    = (float*)carve((size_t)n_nodes * sizeof(float));
    int*   row_ptr = (int*)carve((size_t)(n_nodes + 1) * sizeof(int));
    int*   counter = (int*)carve((size_t)n_nodes * sizeof(int));
    int*   partial = (int*)carve(256 * sizeof(int));
    int*   csr_col = (int*)carve((size_t)nnz_cap * sizeof(int));
    float* csr_w   = (float*)carve((size_t)nnz_cap * sizeof(float));
    if (off > ws_size) return;

    float* out = (float*)d_out;

    const int B = 256;
    int nb = (n_nodes + 255) / 256;

    // ---- graph preprocessing ----
    hipMemsetAsync(csr_col, 0, (size_t)nnz_cap * sizeof(int), stream);
    hipMemsetAsync(csr_w,   0, (size_t)nnz_cap * sizeof(float), stream);
    zero2_kernel<<<(n_nodes + B - 1) / B, B, 0, stream>>>(deg, counter, n_nodes);
    deg_kernel<<<(n_edges + B - 1) / B, B, 0, stream>>>(ei + n_edges, deg, n_edges);
    dinv_kernel<<<(n_nodes + B - 1) / B, B, 0, stream>>>(deg, dinv, n_nodes);
    scan1_kernel<<<nb, 256, 0, stream>>>(deg, row_ptr, partial, n_nodes);
    scan2_kernel<<<1, 256, 0, stream>>>(partial, nb);
    scan3_kernel<<<(n_nodes + B - 1) / B, B, 0, stream>>>(partial, row_ptr, n_nodes);
    fill_kernel<<<(n_edges + n_nodes + B - 1) / B, B, 0, stream>>>(ei, dinv, row_ptr, counter,
                                                                   csr_col, csr_w, n_edges, n_nodes);

    int spmm_grid = (n_nodes + 3) / 4;

    // ---- layer 1 ----
    {
        dim3 g((n_nodes + TM - 1) / TM, (HID + TN - 1) / TN);
        gemm_kernel<<<g, 256, 0, stream>>>(x, W1, Hbuf, n_nodes, IN_DIM, HID);
        spmm_kernel<128><<<spmm_grid, 256, 0, stream>>>(Hbuf, row_ptr, csr_col, csr_w, b1, Bbuf, n_nodes);
    }
    // ---- layer 2 ----
    {
        dim3 g((n_nodes + TM - 1) / TM, (HID + TN - 1) / TN);
        gemm_kernel<<<g, 256, 0, stream>>>(Bbuf, W2, Hbuf, n_nodes, HID, HID);
        spmm_kernel<128><<<spmm_grid, 256, 0, stream>>>(Hbuf, row_ptr, csr_col, csr_w, b2, Bbuf, n_nodes);
    }
    // ---- layer 3 ----
    {
        dim3 g((n_nodes + TM - 1) / TM, (OUT + TN - 1) / TN);
        gemm_kernel<<<g, 256, 0, stream>>>(Bbuf, W3, Hbuf, n_nodes, HID, OUT);
        spmm_kernel<64><<<spmm_grid, 256, 0, stream>>>(Hbuf, row_ptr, csr_col, csr_w, b3, out, n_nodes);
    }
}

// Round 3
// 338.490 us; speedup vs baseline: 1.6836x; 1.0838x over previous
//
#include <hip/hip_runtime.h>
#include <math.h>

// ---------------------------------------------------------------------------
// GCN 3-layer forward:  h = relu(Ahat @ (x @ W) + b)  x3
// Ahat = D^-1/2 (A + I) D^-1/2, CSR-by-dst, rows padded to x8 (pad slots
// col=0,w=0; arrays pre-zeroed) -> tail-free unroll-8 SpMM.
// ---------------------------------------------------------------------------

__global__ void zero2_kernel(int* __restrict__ a, int* __restrict__ b, int n) {
    int i = blockIdx.x * blockDim.x + threadIdx.x;
    if (i < n) { a[i] = 0; b[i] = 0; }
}

__global__ void deg_kernel(const int* __restrict__ dst, int* __restrict__ deg, int E) {
    int i = blockIdx.x * blockDim.x + threadIdx.x;
    if (i < E) atomicAdd(&deg[dst[i]], 1);
}

__global__ void dinv_kernel(const int* __restrict__ deg, float* __restrict__ dinv, int n) {
    int i = blockIdx.x * blockDim.x + threadIdx.x;
    if (i < n) dinv[i] = 1.0f / sqrtf((float)(deg[i] + 1));   // +1 self-loop
}

// --- 3-phase scan over padded row sizes: pad(i) = (deg[i]+1) rounded to x8 --
__global__ __launch_bounds__(256) void scan1_kernel(const int* __restrict__ deg,
                                                    int* __restrict__ row_ptr,
                                                    int* __restrict__ partial, int n) {
    __shared__ int s[256];
    int tid = threadIdx.x;
    int i = blockIdx.x * 256 + tid;
    int v = (i < n) ? ((deg[i] + 8) & ~7) : 0;   // (deg+1) rounded up to mult of 8
    s[tid] = v;
    __syncthreads();
    #pragma unroll
    for (int off = 1; off < 256; off <<= 1) {
        int t = (tid >= off) ? s[tid - off] : 0;
        __syncthreads();
        s[tid] += t;
        __syncthreads();
    }
    if (i < n) row_ptr[i + 1] = s[tid];
    if (tid == 255) partial[blockIdx.x] = s[255];
}

__global__ __launch_bounds__(256) void scan2_kernel(int* __restrict__ partial, int nb) {
    __shared__ int s[256];
    int tid = threadIdx.x;
    int v = (tid < nb) ? partial[tid] : 0;
    s[tid] = v;
    __syncthreads();
    #pragma unroll
    for (int off = 1; off < 256; off <<= 1) {
        int t = (tid >= off) ? s[tid - off] : 0;
        __syncthreads();
        s[tid] += t;
        __syncthreads();
    }
    if (tid < nb) partial[tid] = s[tid] - v;     // exclusive
}

__global__ void scan3_kernel(const int* __restrict__ partial, int* __restrict__ row_ptr, int n) {
    int i = blockIdx.x * blockDim.x + threadIdx.x;
    if (i == 0) row_ptr[0] = 0;
    if (i < n) row_ptr[i + 1] += partial[i >> 8];
}

__global__ void fill_kernel(const int* __restrict__ ei, const float* __restrict__ dinv,
                            const int* __restrict__ row_ptr, int* __restrict__ counter,
                            int* __restrict__ csr_col, float* __restrict__ csr_w,
                            int E, int n) {
    int idx = blockIdx.x * blockDim.x + threadIdx.x;
    int total = E + n;
    if (idx >= total) return;
    int s, d;
    if (idx < E) { s = ei[idx]; d = ei[E + idx]; }
    else         { s = d = idx - E; }
    int pos = row_ptr[d] + atomicAdd(&counter[d], 1);
    csr_col[pos] = s;
    csr_w[pos]   = dinv[s] * dinv[d];
}

// ---------------------------------------------------------------------------
// Tiled fp32 GEMM: C[M,N] = A[M,K] @ B[K,N].  K%32==0, N==TNv (128 or 64).
// 256 threads -> 64xTNv tile, micro-tile 4 rows x (4 or 8) cols.
// Cols per thread are STRIDED (lx*4 and 64+lx*4): a wave's Bs ds_read_b128
// covers 16 consecutive 16B slots -> every bank exactly 2 words (free).
// A staged row-major As[64][36]: b128 stores uniform over banks; a-values
// read as 4 scalar broadcasts (2-way max).
// ---------------------------------------------------------------------------
template <int TNv>
__global__ __launch_bounds__(256) void gemm_kernel(const float* __restrict__ A,
                                                   const float* __restrict__ B,
                                                   float* __restrict__ C,
                                                   int M, int K, int N) {
    __shared__ float As[64][36];        // [m][k], row stride 144B (16B-aligned)
    __shared__ float Bs[32][TNv + 4];   // [k][n], 16B-aligned rows
    int tid = threadIdx.x;
    int lx = tid & 15;          // 16 col-groups
    int ty = tid >> 4;          // 16 row-groups of 4
    int row0 = blockIdx.x * 64;

    float4 acc0[4] = {};
    float4 acc1[4] = {};

    for (int kc = 0; kc < K; kc += 32) {
        // stage A: 64 rows x 32 k (512 float4, 2/thread), row-major
        #pragma unroll
        for (int i = 0; i < 2; ++i) {
            int f = tid + i * 256;
            int r = f >> 3, k4 = (f & 7) << 2;
            int gr = row0 + r;
            float4 v = make_float4(0.f, 0.f, 0.f, 0.f);
            if (gr < M) v = *(const float4*)(A + (size_t)gr * K + kc + k4);
            *(float4*)(&As[r][k4]) = v;
        }
        // stage B: 32 k x TNv cols
        if constexpr (TNv == 128) {
            #pragma unroll
            for (int i = 0; i < 4; ++i) {
                int f = tid + i * 256;
                int r = f >> 5, c4 = (f & 31) << 2;
                *(float4*)(&Bs[r][c4]) = *(const float4*)(B + (size_t)(kc + r) * N + c4);
            }
        } else {
            #pragma unroll
            for (int i = 0; i < 2; ++i) {
                int f = tid + i * 256;
                int r = f >> 4, c4 = (f & 15) << 2;
                *(float4*)(&Bs[r][c4]) = *(const float4*)(B + (size_t)(kc + r) * N + c4);
            }
        }
        __syncthreads();

        #pragma unroll
        for (int kk = 0; kk < 32; ++kk) {
            float a0 = As[ty * 4 + 0][kk];
            float a1 = As[ty * 4 + 1][kk];
            float a2 = As[ty * 4 + 2][kk];
            float a3 = As[ty * 4 + 3][kk];
            float4 b0 = *(const float4*)(&Bs[kk][lx * 4]);
            acc0[0].x = fmaf(a0, b0.x, acc0[0].x); acc0[0].y = fmaf(a0, b0.y, acc0[0].y);
            acc0[0].z = fmaf(a0, b0.z, acc0[0].z); acc0[0].w = fmaf(a0, b0.w, acc0[0].w);
            acc0[1].x = fmaf(a1, b0.x, acc0[1].x); acc0[1].y = fmaf(a1, b0.y, acc0[1].y);
            acc0[1].z = fmaf(a1, b0.z, acc0[1].z); acc0[1].w = fmaf(a1, b0.w, acc0[1].w);
            acc0[2].x = fmaf(a2, b0.x, acc0[2].x); acc0[2].y = fmaf(a2, b0.y, acc0[2].y);
            acc0[2].z = fmaf(a2, b0.z, acc0[2].z); acc0[2].w = fmaf(a2, b0.w, acc0[2].w);
            acc0[3].x = fmaf(a3, b0.x, acc0[3].x); acc0[3].y = fmaf(a3, b0.y, acc0[3].y);
            acc0[3].z = fmaf(a3, b0.z, acc0[3].z); acc0[3].w = fmaf(a3, b0.w, acc0[3].w);
            if constexpr (TNv == 128) {
                float4 b1 = *(const float4*)(&Bs[kk][64 + lx * 4]);
                acc1[0].x = fmaf(a0, b1.x, acc1[0].x); acc1[0].y = fmaf(a0, b1.y, acc1[0].y);
                acc1[0].z = fmaf(a0, b1.z, acc1[0].z); acc1[0].w = fmaf(a0, b1.w, acc1[0].w);
                acc1[1].x = fmaf(a1, b1.x, acc1[1].x); acc1[1].y = fmaf(a1, b1.y, acc1[1].y);
                acc1[1].z = fmaf(a1, b1.z, acc1[1].z); acc1[1].w = fmaf(a1, b1.w, acc1[1].w);
                acc1[2].x = fmaf(a2, b1.x, acc1[2].x); acc1[2].y = fmaf(a2, b1.y, acc1[2].y);
                acc1[2].z = fmaf(a2, b1.z, acc1[2].z); acc1[2].w = fmaf(a2, b1.w, acc1[2].w);
                acc1[3].x = fmaf(a3, b1.x, acc1[3].x); acc1[3].y = fmaf(a3, b1.y, acc1[3].y);
                acc1[3].z = fmaf(a3, b1.z, acc1[3].z); acc1[3].w = fmaf(a3, b1.w, acc1[3].w);
            }
        }
        __syncthreads();
    }

    #pragma unroll
    for (int x = 0; x < 4; ++x) {
        int gr = row0 + ty * 4 + x;
        if (gr < M) {
            *(float4*)(&C[(size_t)gr * N + lx * 4]) = acc0[x];
            if constexpr (TNv == 128)
                *(float4*)(&C[(size_t)gr * N + 64 + lx * 4]) = acc1[x];
        }
    }
}

// ---------------------------------------------------------------------------
// SpMM + bias + relu, rows padded to x8.  One wave per node.
// float4 gathers: 64 lanes x 16B = 1KB/instr = 2 rows (F=128) or 4 (F=64).
// U gathers in flight per lane (8 edges/iter).  Cross-slot combine via
// __shfl_xor at the end; lane-slot 0 writes the output row.
// ---------------------------------------------------------------------------
template <int F>
__global__ __launch_bounds__(256) void spmm_kernel(const float* __restrict__ H,
                                                   const int* __restrict__ row_ptr,
                                                   const int* __restrict__ csr_col,
                                                   const float* __restrict__ csr_w,
                                                   const float* __restrict__ bias,
                                                   float* __restrict__ out,
                                                   int n_nodes) {
    constexpr int LPR = F / 4;      // lanes per row: 32 (F=128) / 16 (F=64)
    constexpr int RPW = 64 / LPR;   // rows per gather instr: 2 / 4
    constexpr int U   = 8 / RPW;    // gathers in flight per lane: 4 / 2
    int wave = threadIdx.x >> 6;
    int lane = threadIdx.x & 63;
    int node = (blockIdx.x << 2) + wave;
    if (node >= n_nodes) return;

    int h  = lane / LPR;            // edge slot within iter
    int fi = (lane % LPR) << 2;     // feature offset
    const float* Hf = H + fi;

    int e0 = row_ptr[node];
    int e1 = row_ptr[node + 1];

    float4 acc[U];
    #pragma unroll
    for (int i = 0; i < U; ++i) acc[i] = make_float4(0.f, 0.f, 0.f, 0.f);

    for (int e = e0; e < e1; e += 8) {
        int   c[U];
        float w[U];
        #pragma unroll
        for (int i = 0; i < U; ++i) {
            int idx = e + i * RPW + h;
            c[i] = csr_col[idx];
            w[i] = csr_w[idx];
        }
        #pragma unroll
        for (int i = 0; i < U; ++i) {
            float4 v = *(const float4*)(Hf + (size_t)c[i] * F);
            acc[i].x = fmaf(w[i], v.x, acc[i].x);
            acc[i].y = fmaf(w[i], v.y, acc[i].y);
            acc[i].z = fmaf(w[i], v.z, acc[i].z);
            acc[i].w = fmaf(w[i], v.w, acc[i].w);
        }
    }

    float4 t = acc[0];
    #pragma unroll
    for (int i = 1; i < U; ++i) {
        t.x += acc[i].x; t.y += acc[i].y; t.z += acc[i].z; t.w += acc[i].w;
    }
    #pragma unroll
    for (int off = LPR; off < 64; off <<= 1) {
        t.x += __shfl_xor(t.x, off);
        t.y += __shfl_xor(t.y, off);
        t.z += __shfl_xor(t.z, off);
        t.w += __shfl_xor(t.w, off);
    }
    if (h == 0) {
        float4 b = *(const float4*)(bias + fi);
        float4 o;
        o.x = fmaxf(t.x + b.x, 0.f);
        o.y = fmaxf(t.y + b.y, 0.f);
        o.z = fmaxf(t.z + b.z, 0.f);
        o.w = fmaxf(t.w + b.w, 0.f);
        *(float4*)(out + (size_t)node * F + fi) = o;
    }
}

// ---------------------------------------------------------------------------

extern "C" void kernel_launch(void* const* d_in, const int* in_sizes, int n_in,
                              void* d_out, int out_size, void* d_ws, size_t ws_size,
                              hipStream_t stream) {
    const float* x  = (const float*)d_in[0];
    const int*   ei = (const int*)d_in[1];     // [2, E] int32
    const float* W1 = (const float*)d_in[2];
    const float* b1 = (const float*)d_in[3];
    const float* W2 = (const float*)d_in[4];
    const float* b2 = (const float*)d_in[5];
    const float* W3 = (const float*)d_in[6];
    const float* b3 = (const float*)d_in[7];

    const int IN_DIM = 256, HID = 128, OUT = 64;
    int n_nodes = in_sizes[0] / IN_DIM;    // 50000
    int n_edges = in_sizes[1] / 2;         // 800000
    int nnz_cap = n_edges + 8 * n_nodes;   // padded CSR upper bound

    // workspace carve-up
    char* ws = (char*)d_ws;
    size_t off = 0;
    auto carve = [&](size_t bytes) { void* p = ws + off; off += (bytes + 255) & ~(size_t)255; return p; };
    float* Hbuf    = (float*)carve((size_t)n_nodes * HID * sizeof(float));
    float* Bbuf    = (float*)carve((size_t)n_nodes * HID * sizeof(float));
    int*   deg     = (int*)carve((size_t)n_nodes * sizeof(int));
    float* dinv    = (float*)carve((size_t)n_nodes * sizeof(float));
    int*   row_ptr = (int*)carve((size_t)(n_nodes + 1) * sizeof(int));
    int*   counter = (int*)carve((size_t)n_nodes * sizeof(int));
    int*   partial = (int*)carve(256 * sizeof(int));
    int*   csr_col = (int*)carve((size_t)nnz_cap * sizeof(int));
    float* csr_w   = (float*)carve((size_t)nnz_cap * sizeof(float));
    if (off > ws_size) return;

    float* out = (float*)d_out;

    const int B = 256;
    int nb = (n_nodes + 255) / 256;

    // ---- graph preprocessing ----
    hipMemsetAsync(csr_col, 0, (size_t)nnz_cap * sizeof(int), stream);
    hipMemsetAsync(csr_w,   0, (size_t)nnz_cap * sizeof(float), stream);
    zero2_kernel<<<(n_nodes + B - 1) / B, B, 0, stream>>>(deg, counter, n_nodes);
    deg_kernel<<<(n_edges + B - 1) / B, B, 0, stream>>>(ei + n_edges, deg, n_edges);
    dinv_kernel<<<(n_nodes + B - 1) / B, B, 0, stream>>>(deg, dinv, n_nodes);
    scan1_kernel<<<nb, 256, 0, stream>>>(deg, row_ptr, partial, n_nodes);
    scan2_kernel<<<1, 256, 0, stream>>>(partial, nb);
    scan3_kernel<<<(n_nodes + B - 1) / B, B, 0, stream>>>(partial, row_ptr, n_nodes);
    fill_kernel<<<(n_edges + n_nodes + B - 1) / B, B, 0, stream>>>(ei, dinv, row_ptr, counter,
                                                                   csr_col, csr_w, n_edges, n_nodes);

    int spmm_grid = (n_nodes + 3) / 4;
    int gemm_grid = (n_nodes + 63) / 64;

    // ---- layer 1 ----
    gemm_kernel<128><<<gemm_grid, 256, 0, stream>>>(x, W1, Hbuf, n_nodes, IN_DIM, HID);
    spmm_kernel<128><<<spmm_grid, 256, 0, stream>>>(Hbuf, row_ptr, csr_col, csr_w, b1, Bbuf, n_nodes);
    // ---- layer 2 ----
    gemm_kernel<128><<<gemm_grid, 256, 0, stream>>>(Bbuf, W2, Hbuf, n_nodes, HID, HID);
    spmm_kernel<128><<<spmm_grid, 256, 0, stream>>>(Hbuf, row_ptr, csr_col, csr_w, b2, Bbuf, n_nodes);
    // ---- layer 3 ----
    gemm_kernel<64><<<gemm_grid, 256, 0, stream>>>(Bbuf, W3, Hbuf, n_nodes, HID, OUT);
    spmm_kernel<64><<<spmm_grid, 256, 0, stream>>>(Hbuf, row_ptr, csr_col, csr_w, b3, out, n_nodes);
}

// Round 4
// 313.503 us; speedup vs baseline: 1.8178x; 1.0797x over previous
//
#include <hip/hip_runtime.h>
#include <math.h>

typedef __attribute__((ext_vector_type(4))) _Float16 half4;

// ---------------------------------------------------------------------------
// GCN 3-layer forward:  h = relu(Ahat @ (x @ W) + b)  x3
// Ahat = D^-1/2 (A + I) D^-1/2, CSR-by-dst, rows padded to x8, packed int2
// {col, w_bits} (pads zero -> w=0). Slot positions precomputed in the degree
// pass (one atomic per edge total). H stored fp16 to halve gather traffic.
// ---------------------------------------------------------------------------

__global__ void zero1_kernel(int* __restrict__ a, int n) {
    int i = blockIdx.x * blockDim.x + threadIdx.x;
    if (i < n) a[i] = 0;
}

// deg + slot position in one atomic pass
__global__ void deg_pos_kernel(const int* __restrict__ dst, int* __restrict__ deg,
                               int* __restrict__ pos, int E) {
    int i = blockIdx.x * blockDim.x + threadIdx.x;
    if (i < E) pos[i] = atomicAdd(&deg[dst[i]], 1);
}

__global__ void dinv_kernel(const int* __restrict__ deg, float* __restrict__ dinv, int n) {
    int i = blockIdx.x * blockDim.x + threadIdx.x;
    if (i < n) dinv[i] = 1.0f / sqrtf((float)(deg[i] + 1));   // +1 self-loop
}

// --- 3-phase scan over padded row sizes: pad(i) = (deg[i]+1) rounded to x8 --
__global__ __launch_bounds__(256) void scan1_kernel(const int* __restrict__ deg,
                                                    int* __restrict__ row_ptr,
                                                    int* __restrict__ partial, int n) {
    __shared__ int s[256];
    int tid = threadIdx.x;
    int i = blockIdx.x * 256 + tid;
    int v = (i < n) ? ((deg[i] + 8) & ~7) : 0;
    s[tid] = v;
    __syncthreads();
    #pragma unroll
    for (int off = 1; off < 256; off <<= 1) {
        int t = (tid >= off) ? s[tid - off] : 0;
        __syncthreads();
        s[tid] += t;
        __syncthreads();
    }
    if (i < n) row_ptr[i + 1] = s[tid];
    if (tid == 255) partial[blockIdx.x] = s[255];
}

__global__ __launch_bounds__(256) void scan2_kernel(int* __restrict__ partial, int nb) {
    __shared__ int s[256];
    int tid = threadIdx.x;
    int v = (tid < nb) ? partial[tid] : 0;
    s[tid] = v;
    __syncthreads();
    #pragma unroll
    for (int off = 1; off < 256; off <<= 1) {
        int t = (tid >= off) ? s[tid - off] : 0;
        __syncthreads();
        s[tid] += t;
        __syncthreads();
    }
    if (tid < nb) partial[tid] = s[tid] - v;     // exclusive
}

__global__ void scan3_kernel(const int* __restrict__ partial, int* __restrict__ row_ptr, int n) {
    int i = blockIdx.x * blockDim.x + threadIdx.x;
    if (i == 0) row_ptr[0] = 0;
    if (i < n) row_ptr[i + 1] += partial[i >> 8];
}

// atomic-free fill: slot was precomputed; pack (col, w) into one int2 store.
__global__ void fill_kernel(const int* __restrict__ ei, const int* __restrict__ pos,
                            const int* __restrict__ deg, const float* __restrict__ dinv,
                            const int* __restrict__ row_ptr, int2* __restrict__ csr,
                            int E, int n) {
    int idx = blockIdx.x * blockDim.x + threadIdx.x;
    if (idx >= E + n) return;
    int s, d, slot;
    if (idx < E) { s = ei[idx]; d = ei[E + idx]; slot = pos[idx]; }
    else         { s = d = idx - E; slot = deg[d]; }    // self-loop takes slot deg[d]
    float w = dinv[s] * dinv[d];
    csr[row_ptr[d] + slot] = make_int2(s, __float_as_int(w));
}

// ---------------------------------------------------------------------------
// Tiled fp32 GEMM -> fp16 out: C[M,TNv] = A[M,K] @ B[K,TNv].  K%32==0.
// 128 threads -> 64 x TNv tile, 8x8 (TNv=128) / 8x4 (TNv=64) micro-tile.
// A staged TRANSPOSED As[k][m] (pad 68) -> a-frag = 2x ds_read_b128, bank-free
// (banks 8*ty spread). B rows 16B-aligned; col pairs lx*4 / 64+lx*4 -> the
// lx>=8 lanes alias banks 2-way (free). 4 b128 per 64 FMA.
// ---------------------------------------------------------------------------
template <int TNv>
__global__ __launch_bounds__(128) void gemm_kernel(const float* __restrict__ A,
                                                   const float* __restrict__ B,
                                                   _Float16* __restrict__ C,
                                                   int M, int K) {
    __shared__ float As[32][68];        // [k][m], row stride 272B
    __shared__ float Bs[32][TNv + 4];   // [k][n]
    int tid = threadIdx.x;
    int lx = tid & 15;          // 16 col-groups of 4
    int ty = tid >> 4;          // 8 row-groups of 8
    int row0 = blockIdx.x * 64;
    int m0 = ty * 8;

    float4 acc0[8] = {};
    float4 acc1[8] = {};

    for (int kc = 0; kc < K; kc += 32) {
        // stage A transposed: 64 rows x 32 k = 512 float4, 4/thread
        #pragma unroll
        for (int i = 0; i < 4; ++i) {
            int g = tid + i * 128;
            int r = g >> 3, k4 = (g & 7) << 2;
            int gr = row0 + r;
            float4 v = make_float4(0.f, 0.f, 0.f, 0.f);
            if (gr < M) v = *(const float4*)(A + (size_t)gr * K + kc + k4);
            As[k4 + 0][r] = v.x;
            As[k4 + 1][r] = v.y;
            As[k4 + 2][r] = v.z;
            As[k4 + 3][r] = v.w;
        }
        // stage B: 32 k x TNv cols
        #pragma unroll
        for (int i = 0; i < TNv / 16; ++i) {
            int g = tid + i * 128;
            int r, c4;
            if constexpr (TNv == 128) { r = g >> 5; c4 = (g & 31) << 2; }
            else                      { r = g >> 4; c4 = (g & 15) << 2; }
            *(float4*)(&Bs[r][c4]) = *(const float4*)(B + (size_t)(kc + r) * TNv + c4);
        }
        __syncthreads();

        #pragma unroll 8
        for (int kk = 0; kk < 32; ++kk) {
            float4 a0 = *(const float4*)(&As[kk][m0]);
            float4 a1 = *(const float4*)(&As[kk][m0 + 4]);
            float4 b0 = *(const float4*)(&Bs[kk][lx * 4]);
            float a[8] = {a0.x, a0.y, a0.z, a0.w, a1.x, a1.y, a1.z, a1.w};
            #pragma unroll
            for (int x = 0; x < 8; ++x) {
                acc0[x].x = fmaf(a[x], b0.x, acc0[x].x);
                acc0[x].y = fmaf(a[x], b0.y, acc0[x].y);
                acc0[x].z = fmaf(a[x], b0.z, acc0[x].z);
                acc0[x].w = fmaf(a[x], b0.w, acc0[x].w);
            }
            if constexpr (TNv == 128) {
                float4 b1 = *(const float4*)(&Bs[kk][64 + lx * 4]);
                #pragma unroll
                for (int x = 0; x < 8; ++x) {
                    acc1[x].x = fmaf(a[x], b1.x, acc1[x].x);
                    acc1[x].y = fmaf(a[x], b1.y, acc1[x].y);
                    acc1[x].z = fmaf(a[x], b1.z, acc1[x].z);
                    acc1[x].w = fmaf(a[x], b1.w, acc1[x].w);
                }
            }
        }
        __syncthreads();
    }

    #pragma unroll
    for (int x = 0; x < 8; ++x) {
        int gr = row0 + m0 + x;
        if (gr < M) {
            half4 h0;
            h0[0] = (_Float16)acc0[x].x; h0[1] = (_Float16)acc0[x].y;
            h0[2] = (_Float16)acc0[x].z; h0[3] = (_Float16)acc0[x].w;
            *(half4*)(&C[(size_t)gr * TNv + lx * 4]) = h0;
            if constexpr (TNv == 128) {
                half4 h1;
                h1[0] = (_Float16)acc1[x].x; h1[1] = (_Float16)acc1[x].y;
                h1[2] = (_Float16)acc1[x].z; h1[3] = (_Float16)acc1[x].w;
                *(half4*)(&C[(size_t)gr * TNv + 64 + lx * 4]) = h1;
            }
        }
    }
}

// ---------------------------------------------------------------------------
// SpMM + bias + relu, fp16 H, rows padded to x8.  One wave per node.
// half4 (8B) gathers: 64 lanes x 8B = 512B/instr; U gathers in flight.
// ---------------------------------------------------------------------------
template <int F>
__global__ __launch_bounds__(256) void spmm_kernel(const _Float16* __restrict__ H,
                                                   const int* __restrict__ row_ptr,
                                                   const int2* __restrict__ csr,
                                                   const float* __restrict__ bias,
                                                   float* __restrict__ out,
                                                   int n_nodes) {
    constexpr int LPR = F / 4;      // lanes per row (half4 chunks): 32 / 16
    constexpr int RPW = 64 / LPR;   // rows per gather instr: 2 / 4
    constexpr int U   = 8 / RPW;    // gathers in flight per lane: 4 / 2
    int wave = threadIdx.x >> 6;
    int lane = threadIdx.x & 63;
    int node = (blockIdx.x << 2) + wave;
    if (node >= n_nodes) return;

    int h  = lane / LPR;            // edge slot within iter
    int fi = (lane % LPR) << 2;     // feature offset (in halves)
    const _Float16* Hf = H + fi;

    int e0 = row_ptr[node];
    int e1 = row_ptr[node + 1];

    float4 acc[U];
    #pragma unroll
    for (int i = 0; i < U; ++i) acc[i] = make_float4(0.f, 0.f, 0.f, 0.f);

    for (int e = e0; e < e1; e += 8) {
        int2 cw[U];
        #pragma unroll
        for (int i = 0; i < U; ++i) cw[i] = csr[e + i * RPW + h];
        #pragma unroll
        for (int i = 0; i < U; ++i) {
            half4 v = *(const half4*)(Hf + (size_t)cw[i].x * F);
            float w = __int_as_float(cw[i].y);
            acc[i].x = fmaf(w, (float)v[0], acc[i].x);
            acc[i].y = fmaf(w, (float)v[1], acc[i].y);
            acc[i].z = fmaf(w, (float)v[2], acc[i].z);
            acc[i].w = fmaf(w, (float)v[3], acc[i].w);
        }
    }

    float4 t = acc[0];
    #pragma unroll
    for (int i = 1; i < U; ++i) {
        t.x += acc[i].x; t.y += acc[i].y; t.z += acc[i].z; t.w += acc[i].w;
    }
    #pragma unroll
    for (int off = LPR; off < 64; off <<= 1) {
        t.x += __shfl_xor(t.x, off);
        t.y += __shfl_xor(t.y, off);
        t.z += __shfl_xor(t.z, off);
        t.w += __shfl_xor(t.w, off);
    }
    if (h == 0) {
        float4 b = *(const float4*)(bias + fi);
        float4 o;
        o.x = fmaxf(t.x + b.x, 0.f);
        o.y = fmaxf(t.y + b.y, 0.f);
        o.z = fmaxf(t.z + b.z, 0.f);
        o.w = fmaxf(t.w + b.w, 0.f);
        *(float4*)(out + (size_t)node * F + fi) = o;
    }
}

// ---------------------------------------------------------------------------

extern "C" void kernel_launch(void* const* d_in, const int* in_sizes, int n_in,
                              void* d_out, int out_size, void* d_ws, size_t ws_size,
                              hipStream_t stream) {
    const float* x  = (const float*)d_in[0];
    const int*   ei = (const int*)d_in[1];     // [2, E] int32
    const float* W1 = (const float*)d_in[2];
    const float* b1 = (const float*)d_in[3];
    const float* W2 = (const float*)d_in[4];
    const float* b2 = (const float*)d_in[5];
    const float* W3 = (const float*)d_in[6];
    const float* b3 = (const float*)d_in[7];

    const int IN_DIM = 256, HID = 128, OUT = 64;
    int n_nodes = in_sizes[0] / IN_DIM;    // 50000
    int n_edges = in_sizes[1] / 2;         // 800000
    int nnz_cap = n_edges + 8 * n_nodes;   // padded CSR upper bound

    // workspace carve-up
    char* ws = (char*)d_ws;
    size_t off = 0;
    auto carve = [&](size_t bytes) { void* p = ws + off; off += (bytes + 255) & ~(size_t)255; return p; };
    _Float16* Hbuf = (_Float16*)carve((size_t)n_nodes * HID * sizeof(_Float16));
    float* Bbuf    = (float*)carve((size_t)n_nodes * HID * sizeof(float));
    int*   deg     = (int*)carve((size_t)n_nodes * sizeof(int));
    float* dinv    = (float*)carve((size_t)n_nodes * sizeof(float));
    int*   row_ptr = (int*)carve((size_t)(n_nodes + 1) * sizeof(int));
    int*   pos     = (int*)carve((size_t)n_edges * sizeof(int));
    int*   partial = (int*)carve(256 * sizeof(int));
    int2*  csr     = (int2*)carve((size_t)nnz_cap * sizeof(int2));
    if (off > ws_size) return;

    float* out = (float*)d_out;

    const int B = 256;
    int nb = (n_nodes + 255) / 256;

    // ---- graph preprocessing ----
    hipMemsetAsync(csr, 0, (size_t)nnz_cap * sizeof(int2), stream);
    zero1_kernel<<<(n_nodes + B - 1) / B, B, 0, stream>>>(deg, n_nodes);
    deg_pos_kernel<<<(n_edges + B - 1) / B, B, 0, stream>>>(ei + n_edges, deg, pos, n_edges);
    dinv_kernel<<<(n_nodes + B - 1) / B, B, 0, stream>>>(deg, dinv, n_nodes);
    scan1_kernel<<<nb, 256, 0, stream>>>(deg, row_ptr, partial, n_nodes);
    scan2_kernel<<<1, 256, 0, stream>>>(partial, nb);
    scan3_kernel<<<(n_nodes + B - 1) / B, B, 0, stream>>>(partial, row_ptr, n_nodes);
    fill_kernel<<<(n_edges + n_nodes + B - 1) / B, B, 0, stream>>>(ei, pos, deg, dinv,
                                                                   row_ptr, csr, n_edges, n_nodes);

    int spmm_grid = (n_nodes + 3) / 4;
    int gemm_grid = (n_nodes + 63) / 64;

    // ---- layer 1 ----
    gemm_kernel<128><<<gemm_grid, 128, 0, stream>>>(x, W1, Hbuf, n_nodes, IN_DIM);
    spmm_kernel<128><<<spmm_grid, 256, 0, stream>>>(Hbuf, row_ptr, csr, b1, Bbuf, n_nodes);
    // ---- layer 2 ----
    gemm_kernel<128><<<gemm_grid, 128, 0, stream>>>(Bbuf, W2, Hbuf, n_nodes, HID);
    spmm_kernel<128><<<spmm_grid, 256, 0, stream>>>(Hbuf, row_ptr, csr, b2, Bbuf, n_nodes);
    // ---- layer 3 ----
    gemm_kernel<64><<<gemm_grid, 128, 0, stream>>>(Bbuf, W3, Hbuf, n_nodes, HID);
    spmm_kernel<64><<<spmm_grid, 256, 0, stream>>>(Hbuf, row_ptr, csr, b3, out, n_nodes);
}

// Round 5
// 232.259 us; speedup vs baseline: 2.4536x; 1.3498x over previous
//
#include <hip/hip_runtime.h>
#include <math.h>

typedef _Float16 half4  __attribute__((ext_vector_type(4)));
typedef _Float16 half8v __attribute__((ext_vector_type(8)));
typedef float    f32x4  __attribute__((ext_vector_type(4)));

// ---------------------------------------------------------------------------
// GCN 3-layer forward:  h = relu(Ahat @ (x @ W) + b)  x3
// Ahat = D^-1/2 (A + I) D^-1/2, CSR-by-dst, rows padded to x8, packed int2
// {col, w_bits}. GEMMs on matrix cores (mfma_f32_16x16x32_f16), fragments
// loaded directly from global (no LDS): A row-major [m][k], B pre-transposed
// fp16 Bt[n][k]. H kept fp16 between layers to halve gather traffic.
// ---------------------------------------------------------------------------

__global__ void zero1_kernel(int* __restrict__ a, int n) {
    int i = blockIdx.x * blockDim.x + threadIdx.x;
    if (i < n) a[i] = 0;
}

// deg + slot position in one atomic pass
__global__ void deg_pos_kernel(const int* __restrict__ dst, int* __restrict__ deg,
                               int* __restrict__ pos, int E) {
    int i = blockIdx.x * blockDim.x + threadIdx.x;
    if (i < E) pos[i] = atomicAdd(&deg[dst[i]], 1);
}

__global__ void dinv_kernel(const int* __restrict__ deg, float* __restrict__ dinv, int n) {
    int i = blockIdx.x * blockDim.x + threadIdx.x;
    if (i < n) dinv[i] = 1.0f / sqrtf((float)(deg[i] + 1));   // +1 self-loop
}

// --- 3-phase scan over padded row sizes: pad(i) = (deg[i]+1) rounded to x8 --
__global__ __launch_bounds__(256) void scan1_kernel(const int* __restrict__ deg,
                                                    int* __restrict__ row_ptr,
                                                    int* __restrict__ partial, int n) {
    __shared__ int s[256];
    int tid = threadIdx.x;
    int i = blockIdx.x * 256 + tid;
    int v = (i < n) ? ((deg[i] + 8) & ~7) : 0;
    s[tid] = v;
    __syncthreads();
    #pragma unroll
    for (int off = 1; off < 256; off <<= 1) {
        int t = (tid >= off) ? s[tid - off] : 0;
        __syncthreads();
        s[tid] += t;
        __syncthreads();
    }
    if (i < n) row_ptr[i + 1] = s[tid];
    if (tid == 255) partial[blockIdx.x] = s[255];
}

__global__ __launch_bounds__(256) void scan2_kernel(int* __restrict__ partial, int nb) {
    __shared__ int s[256];
    int tid = threadIdx.x;
    int v = (tid < nb) ? partial[tid] : 0;
    s[tid] = v;
    __syncthreads();
    #pragma unroll
    for (int off = 1; off < 256; off <<= 1) {
        int t = (tid >= off) ? s[tid - off] : 0;
        __syncthreads();
        s[tid] += t;
        __syncthreads();
    }
    if (tid < nb) partial[tid] = s[tid] - v;     // exclusive
}

__global__ void scan3_kernel(const int* __restrict__ partial, int* __restrict__ row_ptr, int n) {
    int i = blockIdx.x * blockDim.x + threadIdx.x;
    if (i == 0) row_ptr[0] = 0;
    if (i < n) row_ptr[i + 1] += partial[i >> 8];
}

// atomic-free fill: slot was precomputed; pack (col, w) into one int2 store.
__global__ void fill_kernel(const int* __restrict__ ei, const int* __restrict__ pos,
                            const int* __restrict__ deg, const float* __restrict__ dinv,
                            const int* __restrict__ row_ptr, int2* __restrict__ csr,
                            int E, int n) {
    int idx = blockIdx.x * blockDim.x + threadIdx.x;
    if (idx >= E + n) return;
    int s, d, slot;
    if (idx < E) { s = ei[idx]; d = ei[E + idx]; slot = pos[idx]; }
    else         { s = d = idx - E; slot = deg[d]; }    // self-loop takes slot deg[d]
    float w = dinv[s] * dinv[d];
    csr[row_ptr[d] + slot] = make_int2(s, __float_as_int(w));
}

// weight convert + transpose: Bt[n][k] = (fp16) W[k][n]
__global__ void wcvt_kernel(const float* __restrict__ W, _Float16* __restrict__ Bt,
                            int K, int N) {
    int i = blockIdx.x * blockDim.x + threadIdx.x;
    if (i >= K * N) return;
    int n = i / K, k = i % K;
    Bt[(size_t)n * K + k] = (_Float16)W[(size_t)k * N + n];
}

// ---------------------------------------------------------------------------
// MFMA GEMM: C[M,TNv](fp16) = A[M,K] @ Bt[TNv,K]^T, K in {256,128} (cpp-time).
// 256 threads = 4 waves x 32 rows -> 128 rows/block, no LDS/barriers.
// Fragments (16x16x32 f16):
//   A reg j: A[row=lane&15][k=(lane>>4)*8+j]      -> 16B load, row-major A
//   B reg j: B[k=(lane>>4)*8+j][col=lane&15]      -> 16B load from Bt[col][k]
//   D reg j: D[row=(lane>>4)*4+j][col=lane&15]    (m89/m91-verified)
// ---------------------------------------------------------------------------
template <typename TA, int K, int TNv>
__global__ __launch_bounds__(256) void mfma_gemm_kernel(const TA* __restrict__ A,
                                                        const _Float16* __restrict__ Bt,
                                                        _Float16* __restrict__ C,
                                                        int M) {
    constexpr int NF = TNv / 16;
    int lane = threadIdx.x & 63;
    int wave = threadIdx.x >> 6;
    int r  = lane & 15;
    int kg = lane >> 4;
    int row0 = blockIdx.x * 128 + wave * 32;

    f32x4 acc[2][NF];
    #pragma unroll
    for (int mf = 0; mf < 2; ++mf)
        #pragma unroll
        for (int nf = 0; nf < NF; ++nf)
            acc[mf][nf] = (f32x4){0.f, 0.f, 0.f, 0.f};

    int rowA0 = row0 + r;      if (rowA0 > M - 1) rowA0 = M - 1;
    int rowA1 = row0 + 16 + r; if (rowA1 > M - 1) rowA1 = M - 1;
    const TA* pa0 = A + (size_t)rowA0 * K + kg * 8;
    const TA* pa1 = A + (size_t)rowA1 * K + kg * 8;
    const _Float16* pb = Bt + (size_t)r * K + kg * 8;

    #pragma unroll
    for (int kc = 0; kc < K; kc += 32) {
        half8v a0, a1;
        if constexpr (__is_same(TA, float)) {
            float4 l0 = *(const float4*)(pa0 + kc);
            float4 h0 = *(const float4*)(pa0 + kc + 4);
            float4 l1 = *(const float4*)(pa1 + kc);
            float4 h1 = *(const float4*)(pa1 + kc + 4);
            a0[0] = (_Float16)l0.x; a0[1] = (_Float16)l0.y; a0[2] = (_Float16)l0.z; a0[3] = (_Float16)l0.w;
            a0[4] = (_Float16)h0.x; a0[5] = (_Float16)h0.y; a0[6] = (_Float16)h0.z; a0[7] = (_Float16)h0.w;
            a1[0] = (_Float16)l1.x; a1[1] = (_Float16)l1.y; a1[2] = (_Float16)l1.z; a1[3] = (_Float16)l1.w;
            a1[4] = (_Float16)h1.x; a1[5] = (_Float16)h1.y; a1[6] = (_Float16)h1.z; a1[7] = (_Float16)h1.w;
        } else {
            a0 = *(const half8v*)(pa0 + kc);
            a1 = *(const half8v*)(pa1 + kc);
        }
        #pragma unroll
        for (int nf = 0; nf < NF; ++nf) {
            half8v b = *(const half8v*)(pb + (size_t)nf * 16 * K + kc);
            acc[0][nf] = __builtin_amdgcn_mfma_f32_16x16x32_f16(a0, b, acc[0][nf], 0, 0, 0);
            acc[1][nf] = __builtin_amdgcn_mfma_f32_16x16x32_f16(a1, b, acc[1][nf], 0, 0, 0);
        }
    }

    #pragma unroll
    for (int mf = 0; mf < 2; ++mf) {
        #pragma unroll
        for (int j = 0; j < 4; ++j) {
            int row = row0 + mf * 16 + kg * 4 + j;
            if (row < M) {
                #pragma unroll
                for (int nf = 0; nf < NF; ++nf)
                    C[(size_t)row * TNv + nf * 16 + r] = (_Float16)acc[mf][nf][j];
            }
        }
    }
}

// ---------------------------------------------------------------------------
// SpMM + bias + relu, fp16 H, rows padded to x8.  One wave per node.
// half4 (8B) gathers: 64 lanes x 8B = 512B/instr; U gathers in flight.
// ---------------------------------------------------------------------------
template <int F, typename TOut>
__global__ __launch_bounds__(256) void spmm_kernel(const _Float16* __restrict__ H,
                                                   const int* __restrict__ row_ptr,
                                                   const int2* __restrict__ csr,
                                                   const float* __restrict__ bias,
                                                   TOut* __restrict__ out,
                                                   int n_nodes) {
    constexpr int LPR = F / 4;      // lanes per row (half4 chunks): 32 / 16
    constexpr int RPW = 64 / LPR;   // rows per gather instr: 2 / 4
    constexpr int U   = 8 / RPW;    // gathers in flight per lane: 4 / 2
    int wave = threadIdx.x >> 6;
    int lane = threadIdx.x & 63;
    int node = (blockIdx.x << 2) + wave;
    if (node >= n_nodes) return;

    int h  = lane / LPR;            // edge slot within iter
    int fi = (lane % LPR) << 2;     // feature offset (in halves)
    const _Float16* Hf = H + fi;

    int e0 = row_ptr[node];
    int e1 = row_ptr[node + 1];

    float4 acc[U];
    #pragma unroll
    for (int i = 0; i < U; ++i) acc[i] = make_float4(0.f, 0.f, 0.f, 0.f);

    for (int e = e0; e < e1; e += 8) {
        int2 cw[U];
        #pragma unroll
        for (int i = 0; i < U; ++i) cw[i] = csr[e + i * RPW + h];
        #pragma unroll
        for (int i = 0; i < U; ++i) {
            half4 v = *(const half4*)(Hf + (size_t)cw[i].x * F);
            float w = __int_as_float(cw[i].y);
            acc[i].x = fmaf(w, (float)v[0], acc[i].x);
            acc[i].y = fmaf(w, (float)v[1], acc[i].y);
            acc[i].z = fmaf(w, (float)v[2], acc[i].z);
            acc[i].w = fmaf(w, (float)v[3], acc[i].w);
        }
    }

    float4 t = acc[0];
    #pragma unroll
    for (int i = 1; i < U; ++i) {
        t.x += acc[i].x; t.y += acc[i].y; t.z += acc[i].z; t.w += acc[i].w;
    }
    #pragma unroll
    for (int off = LPR; off < 64; off <<= 1) {
        t.x += __shfl_xor(t.x, off);
        t.y += __shfl_xor(t.y, off);
        t.z += __shfl_xor(t.z, off);
        t.w += __shfl_xor(t.w, off);
    }
    if (h == 0) {
        float4 b = *(const float4*)(bias + fi);
        float ox = fmaxf(t.x + b.x, 0.f);
        float oy = fmaxf(t.y + b.y, 0.f);
        float oz = fmaxf(t.z + b.z, 0.f);
        float ow = fmaxf(t.w + b.w, 0.f);
        if constexpr (__is_same(TOut, _Float16)) {
            half4 o;
            o[0] = (_Float16)ox; o[1] = (_Float16)oy; o[2] = (_Float16)oz; o[3] = (_Float16)ow;
            *(half4*)(out + (size_t)node * F + fi) = o;
        } else {
            *(float4*)(out + (size_t)node * F + fi) = make_float4(ox, oy, oz, ow);
        }
    }
}

// ---------------------------------------------------------------------------

extern "C" void kernel_launch(void* const* d_in, const int* in_sizes, int n_in,
                              void* d_out, int out_size, void* d_ws, size_t ws_size,
                              hipStream_t stream) {
    const float* x  = (const float*)d_in[0];
    const int*   ei = (const int*)d_in[1];     // [2, E] int32
    const float* W1 = (const float*)d_in[2];
    const float* b1 = (const float*)d_in[3];
    const float* W2 = (const float*)d_in[4];
    const float* b2 = (const float*)d_in[5];
    const float* W3 = (const float*)d_in[6];
    const float* b3 = (const float*)d_in[7];

    const int IN_DIM = 256, HID = 128, OUT = 64;
    int n_nodes = in_sizes[0] / IN_DIM;    // 50000
    int n_edges = in_sizes[1] / 2;         // 800000
    int nnz_cap = n_edges + 8 * n_nodes;   // padded CSR upper bound

    // workspace carve-up
    char* ws = (char*)d_ws;
    size_t off = 0;
    auto carve = [&](size_t bytes) { void* p = ws + off; off += (bytes + 255) & ~(size_t)255; return p; };
    _Float16* Hbuf = (_Float16*)carve((size_t)n_nodes * HID * sizeof(_Float16));
    _Float16* Bbuf = (_Float16*)carve((size_t)n_nodes * HID * sizeof(_Float16));
    _Float16* Bt1  = (_Float16*)carve((size_t)IN_DIM * HID * sizeof(_Float16));
    _Float16* Bt2  = (_Float16*)carve((size_t)HID * HID * sizeof(_Float16));
    _Float16* Bt3  = (_Float16*)carve((size_t)HID * OUT * sizeof(_Float16));
    int*   deg     = (int*)carve((size_t)n_nodes * sizeof(int));
    float* dinv    = (float*)carve((size_t)n_nodes * sizeof(float));
    int*   row_ptr = (int*)carve((size_t)(n_nodes + 1) * sizeof(int));
    int*   pos     = (int*)carve((size_t)n_edges * sizeof(int));
    int*   partial = (int*)carve(256 * sizeof(int));
    int2*  csr     = (int2*)carve((size_t)nnz_cap * sizeof(int2));
    if (off > ws_size) return;

    float* out = (float*)d_out;

    const int B = 256;
    int nb = (n_nodes + 255) / 256;

    // ---- graph preprocessing ----
    hipMemsetAsync(csr, 0, (size_t)nnz_cap * sizeof(int2), stream);
    zero1_kernel<<<(n_nodes + B - 1) / B, B, 0, stream>>>(deg, n_nodes);
    deg_pos_kernel<<<(n_edges + B - 1) / B, B, 0, stream>>>(ei + n_edges, deg, pos, n_edges);
    dinv_kernel<<<(n_nodes + B - 1) / B, B, 0, stream>>>(deg, dinv, n_nodes);
    scan1_kernel<<<nb, 256, 0, stream>>>(deg, row_ptr, partial, n_nodes);
    scan2_kernel<<<1, 256, 0, stream>>>(partial, nb);
    scan3_kernel<<<(n_nodes + B - 1) / B, B, 0, stream>>>(partial, row_ptr, n_nodes);
    fill_kernel<<<(n_edges + n_nodes + B - 1) / B, B, 0, stream>>>(ei, pos, deg, dinv,
                                                                   row_ptr, csr, n_edges, n_nodes);
    // ---- weight conversion ----
    wcvt_kernel<<<(IN_DIM * HID + B - 1) / B, B, 0, stream>>>(W1, Bt1, IN_DIM, HID);
    wcvt_kernel<<<(HID * HID + B - 1) / B, B, 0, stream>>>(W2, Bt2, HID, HID);
    wcvt_kernel<<<(HID * OUT + B - 1) / B, B, 0, stream>>>(W3, Bt3, HID, OUT);

    int spmm_grid = (n_nodes + 3) / 4;
    int gemm_grid = (n_nodes + 127) / 128;

    // ---- layer 1 ----
    mfma_gemm_kernel<float, 256, 128><<<gemm_grid, 256, 0, stream>>>(x, Bt1, Hbuf, n_nodes);
    spmm_kernel<128, _Float16><<<spmm_grid, 256, 0, stream>>>(Hbuf, row_ptr, csr, b1, Bbuf, n_nodes);
    // ---- layer 2 ----
    mfma_gemm_kernel<_Float16, 128, 128><<<gemm_grid, 256, 0, stream>>>(Bbuf, Bt2, Hbuf, n_nodes);
    spmm_kernel<128, _Float16><<<spmm_grid, 256, 0, stream>>>(Hbuf, row_ptr, csr, b2, Bbuf, n_nodes);
    // ---- layer 3 ----
    mfma_gemm_kernel<_Float16, 128, 64><<<gemm_grid, 256, 0, stream>>>(Bbuf, Bt3, Hbuf, n_nodes);
    spmm_kernel<64, float><<<spmm_grid, 256, 0, stream>>>(Hbuf, row_ptr, csr, b3, out, n_nodes);
}